// Round 1
// baseline (928.824 us; speedup 1.0000x reference)
//
#include <hip/hip_runtime.h>
#include <math.h>

#define NH   8
#define PP   3
#define HP   24      // NH*PP
#define E    512
#define EK   64
#define D    128
#define LL   2048
#define BB   64
#define TT   1024
#define LAT  256
#define HID  512
#define CH   8       // l-chunks in weighted-sum pass
#define CL   256     // chunk length
#define TB   16      // t-rows per MLP block

// ---- workspace offsets (in floats) ----
#define OFF_Q      ((size_t)0)            // 1536
#define OFF_V      ((size_t)2048)         // 12288
#define OFF_SB     ((size_t)14336)        // 24
#define OFF_CV     ((size_t)14400)        // 256
#define OFF_M      ((size_t)14720)        // 1536
#define OFF_COEF   ((size_t)16384)        // 49152
#define OFF_A      ((size_t)65536)        // 98304
#define OFF_ACC    ((size_t)163840)       // 393216
#define OFF_PART   ((size_t)557056)       // 3145728
#define OFF_SCORES ((size_t)3702784)      // 3145728  (total 6,848,512 floats = 27.4 MB)

// K1: q[p][e] = query[p]@W_q + b_q   (batch-independent)
__global__ __launch_bounds__(512) void k_q(const float* __restrict__ query,
                                           const float* __restrict__ W_q,
                                           const float* __restrict__ b_q,
                                           float* __restrict__ qbuf) {
    int p = blockIdx.x, e = threadIdx.x;
    float acc = b_q[e];
    for (int i = 0; i < E; ++i) acc += query[p * E + i] * W_q[(size_t)i * E + e];
    qbuf[p * E + e] = acc;
}

// K2: v[hp][e] = (1/8) * sum_j W_k[e][h*64+j] * q[p][h*64+j];  sbias[hp] likewise from b_k
__global__ __launch_bounds__(512) void k_v(const float* __restrict__ W_k,
                                           const float* __restrict__ b_k,
                                           const float* __restrict__ qbuf,
                                           float* __restrict__ vbuf,
                                           float* __restrict__ sbias) {
    int hp = blockIdx.x;
    int h = hp / PP, p = hp % PP;
    int e = threadIdx.x;
    const float scale = 0.125f;  // 1/sqrt(64)
    float acc = 0.f;
    for (int j = 0; j < EK; ++j)
        acc += W_k[(size_t)e * E + h * EK + j] * qbuf[p * E + h * EK + j];
    vbuf[(size_t)hp * E + e] = acc * scale;
    if (e == 0) {
        float sb = 0.f;
        for (int j = 0; j < EK; ++j) sb += b_k[h * EK + j] * qbuf[p * E + h * EK + j];
        sbias[hp] = sb * scale;
    }
}

// K2b: Cvec[o] = b_o[o] + sum_{h,c} W_o[h*256+128+c][o]   (the "x==1" half)
__global__ __launch_bounds__(256) void k_cvec(const float* __restrict__ W_o,
                                              const float* __restrict__ b_o,
                                              float* __restrict__ Cvec) {
    int o = threadIdx.x;
    float acc = b_o[o];
    for (int h = 0; h < NH; ++h)
        for (int c = 0; c < D; ++c)
            acc += W_o[(size_t)(h * 256 + 128 + c) * LAT + o];
    Cvec[o] = acc;
}

// K3: scores[b][hp][l] = key(b,l,:)·v[hp] + sbias[hp]
__global__ __launch_bounds__(256) void k_scores(const float* __restrict__ timesteps,
                                                const float* __restrict__ w_te,
                                                const float* __restrict__ b_te,
                                                const float* __restrict__ vbuf,
                                                const float* __restrict__ sbias,
                                                float* __restrict__ scores) {
    __shared__ float v_s[HP * E];   // 48 KB
    __shared__ float te_s[2 * E];   // 4 KB
    __shared__ float sb_s[HP];
    int tid = threadIdx.x;
    for (int i = tid; i < HP * E; i += 256) v_s[i] = vbuf[i];
    for (int i = tid; i < E; i += 256) { te_s[i] = w_te[i]; te_s[E + i] = b_te[i]; }
    if (tid < HP) sb_s[tid] = sbias[tid];
    __syncthreads();

    int b = blockIdx.x >> 2;     // 4 segments of 512 l's
    int seg = blockIdx.x & 3;
    int l0 = seg * 512 + tid;    // this thread handles l0 and l0+256
    float ts0 = timesteps[(size_t)b * LL + l0];
    float ts1 = timesteps[(size_t)b * LL + l0 + 256];
    float acc0[HP], acc1[HP];
    #pragma unroll
    for (int hp = 0; hp < HP; ++hp) { acc0[hp] = sb_s[hp]; acc1[hp] = sb_s[hp]; }

    for (int e = 0; e < E; e += 8) {
        float k0[8], k1[8];
        #pragma unroll
        for (int j = 0; j < 8; ++j) {
            float w = te_s[e + j], bb = te_s[E + e + j];
            k0[j] = ts0 * w + bb;
            k1[j] = ts1 * w + bb;
        }
        k0[0] = __sinf(k0[0]);   // sin_mask: e % 8 == 0
        k1[0] = __sinf(k1[0]);
        #pragma unroll
        for (int hp = 0; hp < HP; ++hp) {
            const float4* vp = (const float4*)&v_s[hp * E + e];
            float4 va = vp[0], vb = vp[1];
            acc0[hp] += k0[0]*va.x + k0[1]*va.y + k0[2]*va.z + k0[3]*va.w
                      + k0[4]*vb.x + k0[5]*vb.y + k0[6]*vb.z + k0[7]*vb.w;
            acc1[hp] += k1[0]*va.x + k1[1]*va.y + k1[2]*va.z + k1[3]*va.w
                      + k1[4]*vb.x + k1[5]*vb.y + k1[6]*vb.z + k1[7]*vb.w;
        }
    }
    #pragma unroll
    for (int hp = 0; hp < HP; ++hp) {
        scores[((size_t)b * HP + hp) * LL + l0]       = acc0[hp];
        scores[((size_t)b * HP + hp) * LL + l0 + 256] = acc1[hp];
    }
}

// K4: row max over L
__global__ __launch_bounds__(256) void k_max(const float* __restrict__ scores,
                                             float* __restrict__ mbuf) {
    int row = blockIdx.x, tid = threadIdx.x;
    float mx = -INFINITY;
    for (int l = tid; l < LL; l += 256) mx = fmaxf(mx, scores[(size_t)row * LL + l]);
    __shared__ float red[256];
    red[tid] = mx;
    __syncthreads();
    for (int s = 128; s > 0; s >>= 1) {
        if (tid < s) red[tid] = fmaxf(red[tid], red[tid + s]);
        __syncthreads();
    }
    if (tid == 0) mbuf[row] = red[0];
}

// K5: per-chunk partial weighted sums: part[b][ch][hp][0:128]=num, [128:256]=den
__global__ __launch_bounds__(256) void k_wsum(const float* __restrict__ scores,
                                              const float* __restrict__ mbuf,
                                              const float* __restrict__ X,
                                              const float* __restrict__ M,
                                              float* __restrict__ part) {
    int b = blockIdx.x / CH, ch = blockIdx.x % CH;
    int l0 = ch * CL, tid = threadIdx.x;
    __shared__ float w_s[HP][CL];   // 24 KB
    for (int i = tid; i < HP * CL; i += 256) {
        int hp = i / CL, lc = i % CL;
        w_s[hp][lc] = __expf(scores[((size_t)b * HP + hp) * LL + l0 + lc] - mbuf[b * HP + hp]);
    }
    __syncthreads();

    int c = tid & 127;
    int hh = tid >> 7;   // hp half: 12*hh .. 12*hh+11
    float accn[12], accd[12];
    #pragma unroll
    for (int i = 0; i < 12; ++i) { accn[i] = 0.f; accd[i] = 0.f; }

    for (int lc = 0; lc < CL; lc += 4) {
        float mv[4], xv[4];
        #pragma unroll
        for (int j = 0; j < 4; ++j) {
            size_t l = (size_t)b * LL + l0 + lc + j;
            mv[j] = M[l * D + c];
            xv[j] = X[l * D + c] * mv[j];
        }
        #pragma unroll
        for (int i = 0; i < 12; ++i) {
            const float4 w4 = *(const float4*)&w_s[12 * hh + i][lc];
            accn[i] += w4.x * xv[0] + w4.y * xv[1] + w4.z * xv[2] + w4.w * xv[3];
            accd[i] += w4.x * mv[0] + w4.y * mv[1] + w4.z * mv[2] + w4.w * mv[3];
        }
    }
    #pragma unroll
    for (int i = 0; i < 12; ++i) {
        int hp = 12 * hh + i;
        size_t base = ((size_t)(b * CH + ch) * HP + hp) * 256;
        part[base + c]       = accn[i];
        part[base + 128 + c] = accd[i];
    }
}

// K5b: reduce chunk partials -> accum[b][hp][256]
__global__ __launch_bounds__(256) void k_red(const float* __restrict__ part,
                                             float* __restrict__ accum) {
    int b = blockIdx.x / HP, hp = blockIdx.x % HP, c = threadIdx.x;
    float s = 0.f;
    for (int ch = 0; ch < CH; ++ch)
        s += part[((size_t)(b * CH + ch) * HP + hp) * 256 + c];
    accum[((size_t)b * HP + hp) * 256 + c] = s;
}

// K6: coeffs[b][p][o] = sum_{h,c} (num/den)[b,h,p,c] * W_o[h*256+c][o] + Cvec[o]
__global__ __launch_bounds__(256) void k_coef(const float* __restrict__ accum,
                                              const float* __restrict__ W_o,
                                              const float* __restrict__ Cvec,
                                              float* __restrict__ coeffs) {
    int b = blockIdx.x, o = threadIdx.x;
    __shared__ float ratio[PP][NH][D];   // 12 KB
    for (int i = o; i < PP * NH * D; i += 256) {
        int p = i / (NH * D), h = (i / D) % NH, c = i % D;
        int hp = h * PP + p;
        float n = accum[((size_t)b * HP + hp) * 256 + c];
        float d = accum[((size_t)b * HP + hp) * 256 + 128 + c];
        ratio[p][h][c] = n / d;
    }
    __syncthreads();
    float cv = Cvec[o];
    float a0 = cv, a1 = cv, a2 = cv;
    for (int h = 0; h < NH; ++h) {
        #pragma unroll 4
        for (int c = 0; c < D; ++c) {
            float w = W_o[(size_t)(h * 256 + c) * LAT + o];
            a0 += ratio[0][h][c] * w;
            a1 += ratio[1][h][c] * w;
            a2 += ratio[2][h][c] * w;
        }
    }
    coeffs[((size_t)b * PP + 0) * LAT + o] = a0;
    coeffs[((size_t)b * PP + 1) * LAT + o] = a1;
    coeffs[((size_t)b * PP + 2) * LAT + o] = a2;
}

// K7: a[b][i][j] = coeffs[b][i]@W1[:,j] (+ b1 for i==0)
__global__ __launch_bounds__(512) void k_avec(const float* __restrict__ coeffs,
                                              const float* __restrict__ W1,
                                              const float* __restrict__ b1,
                                              float* __restrict__ abuf) {
    int b = blockIdx.x / 3, i = blockIdx.x % 3;
    int j = threadIdx.x;
    float acc = (i == 0) ? b1[j] : 0.f;
    for (int k = 0; k < LAT; ++k)
        acc += coeffs[((size_t)b * PP + i) * LAT + k] * W1[(size_t)k * HID + j];
    abuf[((size_t)b * 3 + i) * HID + j] = acc;
}

// K8: MLP tail.  h1 = relu(a0 + t*a1 + t^2*a2); h2 = relu(h1@W2+b2); out = h2@W3+b3
__global__ __launch_bounds__(256) void k_mlp(const float* __restrict__ abuf,
                                             const float* __restrict__ yts,
                                             const float* __restrict__ W2,
                                             const float* __restrict__ b2,
                                             const float* __restrict__ W3,
                                             const float* __restrict__ b3,
                                             float* __restrict__ out) {
    int b = blockIdx.x;
    int t0 = blockIdx.y * TB;
    int tid = threadIdx.x;
    __shared__ float a_s[3][HID];     // 6 KB
    __shared__ float h_s[TB][HID];    // 32 KB (h1, then reused for h2)
    __shared__ float tv_s[TB];
    for (int i = tid; i < 3 * HID; i += 256) a_s[i / HID][i % HID] = abuf[(size_t)b * 3 * HID + i];
    if (tid < TB) tv_s[tid] = yts[(size_t)b * TT + t0 + tid];
    __syncthreads();

    // h1
    for (int i = tid; i < TB * HID; i += 256) {
        int r = i / HID, j = i % HID;
        float t = tv_s[r];
        float z = a_s[0][j] + t * (a_s[1][j] + t * a_s[2][j]);
        h_s[r][j] = fmaxf(z, 0.f);
    }
    __syncthreads();

    // h2: each thread owns columns j0, j0+1 for all TB rows
    int j0 = tid * 2;
    float acc[TB][2];
    #pragma unroll
    for (int r = 0; r < TB; ++r) { acc[r][0] = b2[j0]; acc[r][1] = b2[j0 + 1]; }
    for (int k = 0; k < HID; k += 4) {
        float4 hv[TB];
        #pragma unroll
        for (int r = 0; r < TB; ++r) hv[r] = *(const float4*)&h_s[r][k];
        #pragma unroll
        for (int kk = 0; kk < 4; ++kk) {
            float2 w2 = *(const float2*)&W2[(size_t)(k + kk) * HID + j0];
            #pragma unroll
            for (int r = 0; r < TB; ++r) {
                float hval = ((const float*)&hv[r])[kk];
                acc[r][0] += hval * w2.x;
                acc[r][1] += hval * w2.y;
            }
        }
    }
    __syncthreads();
    #pragma unroll
    for (int r = 0; r < TB; ++r) {
        h_s[r][j0]     = fmaxf(acc[r][0], 0.f);
        h_s[r][j0 + 1] = fmaxf(acc[r][1], 0.f);
    }
    __syncthreads();

    // out: thread -> (jo = tid&127, rows rg*8..rg*8+7)
    int jo = tid & 127, rg = tid >> 7;
    float oacc[8];
    #pragma unroll
    for (int r = 0; r < 8; ++r) oacc[r] = b3[jo];
    for (int k = 0; k < HID; k += 4) {
        float4 hv[8];
        #pragma unroll
        for (int r = 0; r < 8; ++r) hv[r] = *(const float4*)&h_s[rg * 8 + r][k];
        #pragma unroll
        for (int kk = 0; kk < 4; ++kk) {
            float w3 = W3[(size_t)(k + kk) * D + jo];
            #pragma unroll
            for (int r = 0; r < 8; ++r) oacc[r] += ((const float*)&hv[r])[kk] * w3;
        }
    }
    #pragma unroll
    for (int r = 0; r < 8; ++r)
        out[((size_t)b * TT + t0 + rg * 8 + r) * D + jo] = oacc[r];
}

extern "C" void kernel_launch(void* const* d_in, const int* in_sizes, int n_in,
                              void* d_out, int out_size, void* d_ws, size_t ws_size,
                              hipStream_t stream) {
    const float* timesteps = (const float*)d_in[0];
    const float* X        = (const float*)d_in[1];
    const float* M        = (const float*)d_in[2];
    const float* yts      = (const float*)d_in[3];
    const float* w_te     = (const float*)d_in[4];
    const float* b_te     = (const float*)d_in[5];
    const float* query    = (const float*)d_in[6];
    const float* W_q      = (const float*)d_in[7];
    const float* b_q      = (const float*)d_in[8];
    const float* W_k      = (const float*)d_in[9];
    const float* b_k      = (const float*)d_in[10];
    const float* W_o      = (const float*)d_in[11];
    const float* b_o      = (const float*)d_in[12];
    const float* W1       = (const float*)d_in[13];
    const float* b1       = (const float*)d_in[14];
    const float* W2       = (const float*)d_in[15];
    const float* b2       = (const float*)d_in[16];
    const float* W3       = (const float*)d_in[17];
    const float* b3       = (const float*)d_in[18];
    float* out = (float*)d_out;
    float* ws  = (float*)d_ws;

    float* qbuf   = ws + OFF_Q;
    float* vbuf   = ws + OFF_V;
    float* sbias  = ws + OFF_SB;
    float* Cvec   = ws + OFF_CV;
    float* mbuf   = ws + OFF_M;
    float* coeffs = ws + OFF_COEF;
    float* abuf   = ws + OFF_A;
    float* accum  = ws + OFF_ACC;
    float* part   = ws + OFF_PART;
    float* scores = ws + OFF_SCORES;

    hipLaunchKernelGGL(k_q,      dim3(PP),          dim3(512), 0, stream, query, W_q, b_q, qbuf);
    hipLaunchKernelGGL(k_v,      dim3(HP),          dim3(512), 0, stream, W_k, b_k, qbuf, vbuf, sbias);
    hipLaunchKernelGGL(k_cvec,   dim3(1),           dim3(256), 0, stream, W_o, b_o, Cvec);
    hipLaunchKernelGGL(k_scores, dim3(BB * 4),      dim3(256), 0, stream, timesteps, w_te, b_te, vbuf, sbias, scores);
    hipLaunchKernelGGL(k_max,    dim3(BB * HP),     dim3(256), 0, stream, scores, mbuf);
    hipLaunchKernelGGL(k_wsum,   dim3(BB * CH),     dim3(256), 0, stream, scores, mbuf, X, M, part);
    hipLaunchKernelGGL(k_red,    dim3(BB * HP),     dim3(256), 0, stream, part, accum);
    hipLaunchKernelGGL(k_coef,   dim3(BB),          dim3(256), 0, stream, accum, W_o, Cvec, coeffs);
    hipLaunchKernelGGL(k_avec,   dim3(BB * 3),      dim3(512), 0, stream, coeffs, W1, b1, abuf);
    hipLaunchKernelGGL(k_mlp,    dim3(BB, TT / TB), dim3(256), 0, stream, abuf, yts, W2, b2, W3, b3, out);
}

// Round 2
// 386.857 us; speedup vs baseline: 2.4009x; 2.4009x over previous
//
#include <hip/hip_runtime.h>
#include <math.h>

#define NH   8
#define PP   3
#define HP   24      // NH*PP
#define E    512
#define EK   64
#define D    128
#define LL   2048
#define BB   64
#define TT   1024
#define LAT  256
#define HID  512
#define CH   8       // l-chunks in weighted-sum pass
#define CL   256     // chunk length

typedef __attribute__((ext_vector_type(8))) short bf16x8;
typedef __attribute__((ext_vector_type(4))) float f32x4;

// ---- workspace offsets (in floats) ----
#define OFF_Q      ((size_t)0)            // 1536
#define OFF_V      ((size_t)2048)         // 12288
#define OFF_SB     ((size_t)14336)        // 24
#define OFF_CV     ((size_t)14400)        // 256
#define OFF_M      ((size_t)14720)        // 1536
#define OFF_COEF   ((size_t)16384)        // 49152
#define OFF_A      ((size_t)65536)        // 98304
#define OFF_ACC    ((size_t)163840)       // 393216
#define OFF_PART   ((size_t)557056)       // 3145728
#define OFF_SCORES ((size_t)3702784)      // 3145728  (W2T/W3T overlay here after k_wsum)

__device__ inline ushort f2bf(float x) {
    union { float f; uint u; } v; v.f = x;
    uint r = v.u + 0x7fffu + ((v.u >> 16) & 1u);
    return (ushort)(r >> 16);
}

// K1: q[p][e] = query[p]@W_q + b_q   (batch-independent)
__global__ __launch_bounds__(512) void k_q(const float* __restrict__ query,
                                           const float* __restrict__ W_q,
                                           const float* __restrict__ b_q,
                                           float* __restrict__ qbuf) {
    int p = blockIdx.x, e = threadIdx.x;
    float acc = b_q[e];
    for (int i = 0; i < E; ++i) acc += query[p * E + i] * W_q[(size_t)i * E + e];
    qbuf[p * E + e] = acc;
}

// K2: v[hp][e] = (1/8) * sum_j W_k[e][h*64+j] * q[p][h*64+j];  sbias[hp] likewise from b_k
__global__ __launch_bounds__(512) void k_v(const float* __restrict__ W_k,
                                           const float* __restrict__ b_k,
                                           const float* __restrict__ qbuf,
                                           float* __restrict__ vbuf,
                                           float* __restrict__ sbias) {
    int hp = blockIdx.x;
    int h = hp / PP, p = hp % PP;
    int e = threadIdx.x;
    const float scale = 0.125f;  // 1/sqrt(64)
    float acc = 0.f;
    for (int j = 0; j < EK; ++j)
        acc += W_k[(size_t)e * E + h * EK + j] * qbuf[p * E + h * EK + j];
    vbuf[(size_t)hp * E + e] = acc * scale;
    if (e == 0) {
        float sb = 0.f;
        for (int j = 0; j < EK; ++j) sb += b_k[h * EK + j] * qbuf[p * E + h * EK + j];
        sbias[hp] = sb * scale;
    }
}

// K2b: Cvec[o] = b_o[o] + sum_{h,c} W_o[h*256+128+c][o]   (the "x==1" half)
__global__ __launch_bounds__(256) void k_cvec(const float* __restrict__ W_o,
                                              const float* __restrict__ b_o,
                                              float* __restrict__ Cvec) {
    int o = threadIdx.x;
    float acc = b_o[o];
    for (int h = 0; h < NH; ++h)
        for (int c = 0; c < D; ++c)
            acc += W_o[(size_t)(h * 256 + 128 + c) * LAT + o];
    Cvec[o] = acc;
}

// K3: scores[b][hp][l] = key(b,l,:)·v[hp] + sbias[hp]
__global__ __launch_bounds__(256) void k_scores(const float* __restrict__ timesteps,
                                                const float* __restrict__ w_te,
                                                const float* __restrict__ b_te,
                                                const float* __restrict__ vbuf,
                                                const float* __restrict__ sbias,
                                                float* __restrict__ scores) {
    __shared__ float v_s[HP * E];   // 48 KB
    __shared__ float te_s[2 * E];   // 4 KB
    __shared__ float sb_s[HP];
    int tid = threadIdx.x;
    for (int i = tid; i < HP * E; i += 256) v_s[i] = vbuf[i];
    for (int i = tid; i < E; i += 256) { te_s[i] = w_te[i]; te_s[E + i] = b_te[i]; }
    if (tid < HP) sb_s[tid] = sbias[tid];
    __syncthreads();

    int b = blockIdx.x >> 2;     // 4 segments of 512 l's
    int seg = blockIdx.x & 3;
    int l0 = seg * 512 + tid;    // this thread handles l0 and l0+256
    float ts0 = timesteps[(size_t)b * LL + l0];
    float ts1 = timesteps[(size_t)b * LL + l0 + 256];
    float acc0[HP], acc1[HP];
    #pragma unroll
    for (int hp = 0; hp < HP; ++hp) { acc0[hp] = sb_s[hp]; acc1[hp] = sb_s[hp]; }

    for (int e = 0; e < E; e += 8) {
        float k0[8], k1[8];
        #pragma unroll
        for (int j = 0; j < 8; ++j) {
            float w = te_s[e + j], bb = te_s[E + e + j];
            k0[j] = ts0 * w + bb;
            k1[j] = ts1 * w + bb;
        }
        k0[0] = __sinf(k0[0]);   // sin_mask: e % 8 == 0
        k1[0] = __sinf(k1[0]);
        #pragma unroll
        for (int hp = 0; hp < HP; ++hp) {
            const float4* vp = (const float4*)&v_s[hp * E + e];
            float4 va = vp[0], vb = vp[1];
            acc0[hp] += k0[0]*va.x + k0[1]*va.y + k0[2]*va.z + k0[3]*va.w
                      + k0[4]*vb.x + k0[5]*vb.y + k0[6]*vb.z + k0[7]*vb.w;
            acc1[hp] += k1[0]*va.x + k1[1]*va.y + k1[2]*va.z + k1[3]*va.w
                      + k1[4]*vb.x + k1[5]*vb.y + k1[6]*vb.z + k1[7]*vb.w;
        }
    }
    #pragma unroll
    for (int hp = 0; hp < HP; ++hp) {
        scores[((size_t)b * HP + hp) * LL + l0]       = acc0[hp];
        scores[((size_t)b * HP + hp) * LL + l0 + 256] = acc1[hp];
    }
}

// K4: row max over L
__global__ __launch_bounds__(256) void k_max(const float* __restrict__ scores,
                                             float* __restrict__ mbuf) {
    int row = blockIdx.x, tid = threadIdx.x;
    float mx = -INFINITY;
    for (int l = tid; l < LL; l += 256) mx = fmaxf(mx, scores[(size_t)row * LL + l]);
    __shared__ float red[256];
    red[tid] = mx;
    __syncthreads();
    for (int s = 128; s > 0; s >>= 1) {
        if (tid < s) red[tid] = fmaxf(red[tid], red[tid + s]);
        __syncthreads();
    }
    if (tid == 0) mbuf[row] = red[0];
}

// K5: per-chunk partial weighted sums: part[b][ch][hp][0:128]=num, [128:256]=den
__global__ __launch_bounds__(256) void k_wsum(const float* __restrict__ scores,
                                              const float* __restrict__ mbuf,
                                              const float* __restrict__ X,
                                              const float* __restrict__ M,
                                              float* __restrict__ part) {
    int b = blockIdx.x / CH, ch = blockIdx.x % CH;
    int l0 = ch * CL, tid = threadIdx.x;
    __shared__ float w_s[HP][CL];   // 24 KB
    for (int i = tid; i < HP * CL; i += 256) {
        int hp = i / CL, lc = i % CL;
        w_s[hp][lc] = __expf(scores[((size_t)b * HP + hp) * LL + l0 + lc] - mbuf[b * HP + hp]);
    }
    __syncthreads();

    int c = tid & 127;
    int hh = tid >> 7;   // hp half: 12*hh .. 12*hh+11
    float accn[12], accd[12];
    #pragma unroll
    for (int i = 0; i < 12; ++i) { accn[i] = 0.f; accd[i] = 0.f; }

    for (int lc = 0; lc < CL; lc += 4) {
        float mv[4], xv[4];
        #pragma unroll
        for (int j = 0; j < 4; ++j) {
            size_t l = (size_t)b * LL + l0 + lc + j;
            mv[j] = M[l * D + c];
            xv[j] = X[l * D + c] * mv[j];
        }
        #pragma unroll
        for (int i = 0; i < 12; ++i) {
            const float4 w4 = *(const float4*)&w_s[12 * hh + i][lc];
            accn[i] += w4.x * xv[0] + w4.y * xv[1] + w4.z * xv[2] + w4.w * xv[3];
            accd[i] += w4.x * mv[0] + w4.y * mv[1] + w4.z * mv[2] + w4.w * mv[3];
        }
    }
    #pragma unroll
    for (int i = 0; i < 12; ++i) {
        int hp = 12 * hh + i;
        size_t base = ((size_t)(b * CH + ch) * HP + hp) * 256;
        part[base + c]       = accn[i];
        part[base + 128 + c] = accd[i];
    }
}

// K5b: reduce chunk partials -> accum[b][hp][256]
__global__ __launch_bounds__(256) void k_red(const float* __restrict__ part,
                                             float* __restrict__ accum) {
    int b = blockIdx.x / HP, hp = blockIdx.x % HP, c = threadIdx.x;
    float s = 0.f;
    for (int ch = 0; ch < CH; ++ch)
        s += part[((size_t)(b * CH + ch) * HP + hp) * 256 + c];
    accum[((size_t)b * HP + hp) * 256 + c] = s;
}

// K5c: convert W2 -> W2T bf16 [n][k], W3 -> W3T bf16 [n][k]  (into scores overlay)
__global__ __launch_bounds__(256) void k_cvt(const float* __restrict__ W2,
                                             const float* __restrict__ W3,
                                             ushort* __restrict__ W2T,
                                             ushort* __restrict__ W3T) {
    int idx = blockIdx.x * 256 + threadIdx.x;
    if (idx < HID * HID) {
        int k = idx >> 9, n = idx & 511;          // coalesced read of W2[k][n]
        W2T[(size_t)n * HID + k] = f2bf(W2[idx]);
    } else {
        int j = idx - HID * HID;                  // j < 512*128
        int k = j >> 7, n = j & 127;              // coalesced read of W3[k][n]
        W3T[(size_t)n * HID + k] = f2bf(W3[j]);
    }
}

// K6: coeffs[b][p][o] = sum_{h,c} (num/den)[b,h,p,c] * W_o[h*256+c][o] + Cvec[o]
__global__ __launch_bounds__(256) void k_coef(const float* __restrict__ accum,
                                              const float* __restrict__ W_o,
                                              const float* __restrict__ Cvec,
                                              float* __restrict__ coeffs) {
    int b = blockIdx.x, o = threadIdx.x;
    __shared__ float ratio[PP][NH][D];   // 12 KB
    for (int i = o; i < PP * NH * D; i += 256) {
        int p = i / (NH * D), h = (i / D) % NH, c = i % D;
        int hp = h * PP + p;
        float n = accum[((size_t)b * HP + hp) * 256 + c];
        float d = accum[((size_t)b * HP + hp) * 256 + 128 + c];
        ratio[p][h][c] = n / d;
    }
    __syncthreads();
    float cv = Cvec[o];
    float a0 = cv, a1 = cv, a2 = cv;
    for (int h = 0; h < NH; ++h) {
        #pragma unroll 4
        for (int c = 0; c < D; ++c) {
            float w = W_o[(size_t)(h * 256 + c) * LAT + o];
            a0 += ratio[0][h][c] * w;
            a1 += ratio[1][h][c] * w;
            a2 += ratio[2][h][c] * w;
        }
    }
    coeffs[((size_t)b * PP + 0) * LAT + o] = a0;
    coeffs[((size_t)b * PP + 1) * LAT + o] = a1;
    coeffs[((size_t)b * PP + 2) * LAT + o] = a2;
}

// K7: a[b][i][j] = coeffs[b][i]@W1[:,j] (+ b1 for i==0)
__global__ __launch_bounds__(512) void k_avec(const float* __restrict__ coeffs,
                                              const float* __restrict__ W1,
                                              const float* __restrict__ b1,
                                              float* __restrict__ abuf) {
    int b = blockIdx.x / 3, i = blockIdx.x % 3;
    int j = threadIdx.x;
    float acc = (i == 0) ? b1[j] : 0.f;
    for (int k = 0; k < LAT; ++k)
        acc += coeffs[((size_t)b * PP + i) * LAT + k] * W1[(size_t)k * HID + j];
    abuf[((size_t)b * 3 + i) * HID + j] = acc;
}

// K8: fused MFMA MLP tail. Tile = 128 t-rows. h1(bf16,LDS) -> GEMM1(W2T) -> h2(bf16,LDS) -> GEMM2(W3T)
__global__ __launch_bounds__(512, 2) void k_mlp2(const float* __restrict__ abuf,
                                                 const float* __restrict__ yts,
                                                 const ushort* __restrict__ W2T,
                                                 const float* __restrict__ b2,
                                                 const ushort* __restrict__ W3T,
                                                 const float* __restrict__ b3,
                                                 float* __restrict__ out) {
    __shared__ ushort hbuf[128 * HID];    // 128 KiB, XOR-swizzled rows (1 KiB row stride)
    int b = blockIdx.x;
    int t0 = blockIdx.y * 128;
    int tid = threadIdx.x;
    const float* a0p = abuf + (size_t)b * 3 * HID;
    const float* a1p = a0p + HID;
    const float* a2p = a1p + HID;

    // h1 = relu(a0 + t*a1 + t^2*a2), bf16 -> LDS (swizzled)
    for (int ii = tid; ii < 128 * 256; ii += 512) {
        int r = ii >> 8, jp = (ii & 255) * 2;
        float t = yts[(size_t)b * TT + t0 + r];
        float z0 = a0p[jp]     + t * (a1p[jp]     + t * a2p[jp]);
        float z1 = a0p[jp + 1] + t * (a1p[jp + 1] + t * a2p[jp + 1]);
        uint pk = (uint)f2bf(fmaxf(z0, 0.f)) | ((uint)f2bf(fmaxf(z1, 0.f)) << 16);
        uint byte = (uint)(r * 1024 + jp * 2);
        *(uint*)((char*)hbuf + (byte ^ ((uint)(r & 7) << 4))) = pk;
    }
    __syncthreads();

    int wid = tid >> 6, lane = tid & 63;
    int ln = lane & 15, hi = lane >> 4;
    int wr = wid >> 2, wc = wid & 3;   // wave tile: rows wr*64, cols wc*128 (GEMM1)

    // ---- GEMM1: h2 = relu(h1 @ W2 + b2) ----
    f32x4 acc[4][8];
    #pragma unroll
    for (int n = 0; n < 8; ++n) {
        float bv = b2[wc * 128 + n * 16 + ln];
        #pragma unroll
        for (int m = 0; m < 4; ++m) acc[m][n] = (f32x4){bv, bv, bv, bv};
    }
    for (int k0 = 0; k0 < HID; k0 += 32) {
        bf16x8 af[4], bf[8];
        #pragma unroll
        for (int m = 0; m < 4; ++m) {
            int r = wr * 64 + m * 16 + ln;
            uint byte = (uint)(r * 1024 + (k0 + 8 * hi) * 2);
            af[m] = *(const bf16x8*)((const char*)hbuf + (byte ^ ((uint)(r & 7) << 4)));
        }
        #pragma unroll
        for (int n = 0; n < 8; ++n) {
            int c = wc * 128 + n * 16 + ln;
            bf[n] = *(const bf16x8*)(W2T + (size_t)c * HID + k0 + 8 * hi);
        }
        #pragma unroll
        for (int m = 0; m < 4; ++m)
            #pragma unroll
            for (int n = 0; n < 8; ++n)
                acc[m][n] = __builtin_amdgcn_mfma_f32_16x16x32_bf16(af[m], bf[n], acc[m][n], 0, 0, 0);
    }
    __syncthreads();   // everyone done reading h1

    // relu + bf16 -> LDS as h2 (same buffer, same swizzle)
    #pragma unroll
    for (int m = 0; m < 4; ++m)
        #pragma unroll
        for (int n = 0; n < 8; ++n)
            #pragma unroll
            for (int reg = 0; reg < 4; ++reg) {
                int r = wr * 64 + m * 16 + 4 * hi + reg;
                int c = wc * 128 + n * 16 + ln;
                ushort hv = f2bf(fmaxf(acc[m][n][reg], 0.f));
                uint byte = (uint)(r * 1024 + c * 2);
                *(ushort*)((char*)hbuf + (byte ^ ((uint)(r & 7) << 4))) = hv;
            }
    __syncthreads();

    // ---- GEMM2: out = h2 @ W3 + b3 ----  wave tile: rows wr*64, cols wc*32
    f32x4 acc2[4][2];
    #pragma unroll
    for (int n = 0; n < 2; ++n) {
        float bv = b3[wc * 32 + n * 16 + ln];
        #pragma unroll
        for (int m = 0; m < 4; ++m) acc2[m][n] = (f32x4){bv, bv, bv, bv};
    }
    for (int k0 = 0; k0 < HID; k0 += 32) {
        bf16x8 af[4], bf[2];
        #pragma unroll
        for (int m = 0; m < 4; ++m) {
            int r = wr * 64 + m * 16 + ln;
            uint byte = (uint)(r * 1024 + (k0 + 8 * hi) * 2);
            af[m] = *(const bf16x8*)((const char*)hbuf + (byte ^ ((uint)(r & 7) << 4)));
        }
        #pragma unroll
        for (int n = 0; n < 2; ++n) {
            int c = wc * 32 + n * 16 + ln;
            bf[n] = *(const bf16x8*)(W3T + (size_t)c * HID + k0 + 8 * hi);
        }
        #pragma unroll
        for (int m = 0; m < 4; ++m)
            #pragma unroll
            for (int n = 0; n < 2; ++n)
                acc2[m][n] = __builtin_amdgcn_mfma_f32_16x16x32_bf16(af[m], bf[n], acc2[m][n], 0, 0, 0);
    }

    #pragma unroll
    for (int m = 0; m < 4; ++m)
        #pragma unroll
        for (int n = 0; n < 2; ++n)
            #pragma unroll
            for (int reg = 0; reg < 4; ++reg) {
                int r = wr * 64 + m * 16 + 4 * hi + reg;
                int c = wc * 32 + n * 16 + ln;
                out[((size_t)(b * TT + t0 + r)) * D + c] = acc2[m][n][reg];
            }
}

extern "C" void kernel_launch(void* const* d_in, const int* in_sizes, int n_in,
                              void* d_out, int out_size, void* d_ws, size_t ws_size,
                              hipStream_t stream) {
    const float* timesteps = (const float*)d_in[0];
    const float* X        = (const float*)d_in[1];
    const float* M        = (const float*)d_in[2];
    const float* yts      = (const float*)d_in[3];
    const float* w_te     = (const float*)d_in[4];
    const float* b_te     = (const float*)d_in[5];
    const float* query    = (const float*)d_in[6];
    const float* W_q      = (const float*)d_in[7];
    const float* b_q      = (const float*)d_in[8];
    const float* W_k      = (const float*)d_in[9];
    const float* b_k      = (const float*)d_in[10];
    const float* W_o      = (const float*)d_in[11];
    const float* b_o      = (const float*)d_in[12];
    const float* W1       = (const float*)d_in[13];
    const float* b1       = (const float*)d_in[14];
    const float* W2       = (const float*)d_in[15];
    const float* b2       = (const float*)d_in[16];
    const float* W3       = (const float*)d_in[17];
    const float* b3       = (const float*)d_in[18];
    float* out = (float*)d_out;
    float* ws  = (float*)d_ws;

    float* qbuf   = ws + OFF_Q;
    float* vbuf   = ws + OFF_V;
    float* sbias  = ws + OFF_SB;
    float* Cvec   = ws + OFF_CV;
    float* mbuf   = ws + OFF_M;
    float* coeffs = ws + OFF_COEF;
    float* abuf   = ws + OFF_A;
    float* accum  = ws + OFF_ACC;
    float* part   = ws + OFF_PART;
    float* scores = ws + OFF_SCORES;
    ushort* W2T   = (ushort*)(ws + OFF_SCORES);          // overlay: scores dead after k_wsum
    ushort* W3T   = W2T + (size_t)HID * HID;

    hipLaunchKernelGGL(k_q,      dim3(PP),        dim3(512), 0, stream, query, W_q, b_q, qbuf);
    hipLaunchKernelGGL(k_v,      dim3(HP),        dim3(512), 0, stream, W_k, b_k, qbuf, vbuf, sbias);
    hipLaunchKernelGGL(k_cvec,   dim3(1),         dim3(256), 0, stream, W_o, b_o, Cvec);
    hipLaunchKernelGGL(k_scores, dim3(BB * 4),    dim3(256), 0, stream, timesteps, w_te, b_te, vbuf, sbias, scores);
    hipLaunchKernelGGL(k_max,    dim3(BB * HP),   dim3(256), 0, stream, scores, mbuf);
    hipLaunchKernelGGL(k_wsum,   dim3(BB * CH),   dim3(256), 0, stream, scores, mbuf, X, M, part);
    hipLaunchKernelGGL(k_red,    dim3(BB * HP),   dim3(256), 0, stream, part, accum);
    hipLaunchKernelGGL(k_cvt,    dim3((HID * HID + HID * D) / 256), dim3(256), 0, stream, W2, W3, W2T, W3T);
    hipLaunchKernelGGL(k_coef,   dim3(BB),        dim3(256), 0, stream, accum, W_o, Cvec, coeffs);
    hipLaunchKernelGGL(k_avec,   dim3(BB * 3),    dim3(512), 0, stream, coeffs, W1, b1, abuf);
    hipLaunchKernelGGL(k_mlp2,   dim3(BB, TT / 128), dim3(512), 0, stream, abuf, yts, W2T, b2, W3T, b3, out);
}

// Round 3
// 333.903 us; speedup vs baseline: 2.7817x; 1.1586x over previous
//
#include <hip/hip_runtime.h>
#include <math.h>

#define NH   8
#define PP   3
#define HP   24      // NH*PP
#define E    512
#define EK   64
#define D    128
#define LL   2048
#define BB   64
#define TT   1024
#define LAT  256
#define HID  512
#define CH   8       // l-chunks in weighted-sum pass
#define CL   256     // chunk length

typedef __attribute__((ext_vector_type(8))) short bf16x8;
typedef __attribute__((ext_vector_type(4))) float f32x4;

// ---- workspace offsets (in floats) ----
#define OFF_Q      ((size_t)0)            // 1536
#define OFF_VS     ((size_t)2048)         // 1536 (vsin 24x64)
#define OFF_WA     ((size_t)4096)         // 24
#define OFF_WB     ((size_t)4128)         // 24
#define OFF_SB     ((size_t)4160)         // 24
#define OFF_CV     ((size_t)4224)         // 256
#define OFF_PMAX   ((size_t)4608)         // 12288 (64 x 8 x 24)
#define OFF_COEF   ((size_t)24576)        // 49152
#define OFF_P2     ((size_t)81920)        // 393216 (part2; abuf overlays after k_cred)
#define OFF_A      ((size_t)81920)        // 98304  (abuf, overlays part2)
#define OFF_PART   ((size_t)475136)       // 3145728 (part; W2T/W3T overlay after k_coefp)
#define OFF_SC     ((size_t)3620864)      // 3145728 (scores)  total = 6,766,592 floats = 27.07 MB

__device__ inline ushort f2bf(float x) {
    union { float f; uint u; } v; v.f = x;
    uint r = v.u + 0x7fffu + ((v.u >> 16) & 1u);
    return (ushort)(r >> 16);
}

// K1: q[p][e] = query[p]@W_q + b_q   (batch-independent)
__global__ __launch_bounds__(512) void k_q(const float* __restrict__ query,
                                           const float* __restrict__ W_q,
                                           const float* __restrict__ b_q,
                                           float* __restrict__ qbuf) {
    int p = blockIdx.x, e = threadIdx.x;
    float acc = b_q[e];
    for (int i = 0; i < E; ++i) acc += query[p * E + i] * W_q[(size_t)i * E + e];
    qbuf[p * E + e] = acc;
}

// K2: per (hp): v[e] = (1/8)*sum_j W_k[e][h*64+j] q[p][..]; emit vsin (e%8==0 cols),
//     wA = sum v*w_te, wB = sum v*b_te, sbias.
__global__ __launch_bounds__(512) void k_v(const float* __restrict__ W_k,
                                           const float* __restrict__ b_k,
                                           const float* __restrict__ qbuf,
                                           const float* __restrict__ w_te,
                                           const float* __restrict__ b_te,
                                           float* __restrict__ vsin,
                                           float* __restrict__ wA,
                                           float* __restrict__ wB,
                                           float* __restrict__ sbias) {
    int hp = blockIdx.x;
    int h = hp / PP, p = hp % PP;
    int e = threadIdx.x;
    const float scale = 0.125f;  // 1/sqrt(64)
    float acc = 0.f;
    for (int j = 0; j < EK; ++j)
        acc += W_k[(size_t)e * E + h * EK + j] * qbuf[p * E + h * EK + j];
    float v = acc * scale;
    if ((e & 7) == 0) vsin[hp * 64 + (e >> 3)] = v;
    __shared__ float r1[512], r2[512];
    r1[e] = v * w_te[e];
    r2[e] = v * b_te[e];
    __syncthreads();
    for (int s = 256; s > 0; s >>= 1) {
        if (e < s) { r1[e] += r1[e + s]; r2[e] += r2[e + s]; }
        __syncthreads();
    }
    if (e == 0) {
        wA[hp] = r1[0];
        wB[hp] = r2[0];
        float sb = 0.f;
        for (int j = 0; j < EK; ++j) sb += b_k[h * EK + j] * qbuf[p * E + h * EK + j];
        sbias[hp] = sb * scale;
    }
}

// K2b: Cvec[o] = b_o[o] + sum_{h,c} W_o[h*256+128+c][o]   (the "x==1" half)
__global__ __launch_bounds__(256) void k_cvec(const float* __restrict__ W_o,
                                              const float* __restrict__ b_o,
                                              float* __restrict__ Cvec) {
    int o = threadIdx.x;
    float acc = b_o[o];
    for (int h = 0; h < NH; ++h)
        for (int c = 0; c < D; ++c)
            acc += W_o[(size_t)(h * 256 + 128 + c) * LAT + o];
    Cvec[o] = acc;
}

// K3: scores[b][hp][l] = ts*wA[hp] + wB[hp] + sb[hp] + sum_j (sin(kj)-kj)*vsin[hp][j]
//     + per-(b,seg) partial max -> pmax
__global__ __launch_bounds__(256) void k_scores(const float* __restrict__ timesteps,
                                                const float* __restrict__ w_te,
                                                const float* __restrict__ b_te,
                                                const float* __restrict__ vsin,
                                                const float* __restrict__ wA,
                                                const float* __restrict__ wB,
                                                const float* __restrict__ sb,
                                                float* __restrict__ scores,
                                                float* __restrict__ pmax) {
    __shared__ float vs_s[HP * 64];   // 6 KB
    __shared__ float w8_s[64], b8_s[64];
    __shared__ float wA_s[HP], wB_s[HP], sb_s[HP];
    __shared__ float wmax_s[HP][4];
    int tid = threadIdx.x;
    for (int i = tid; i < HP * 64; i += 256) vs_s[i] = vsin[i];
    if (tid < 64) { w8_s[tid] = w_te[tid * 8]; b8_s[tid] = b_te[tid * 8]; }
    if (tid < HP) { wA_s[tid] = wA[tid]; wB_s[tid] = wB[tid]; sb_s[tid] = sb[tid]; }
    __syncthreads();

    int b = blockIdx.x >> 3, seg = blockIdx.x & 7;
    int l = seg * 256 + tid;
    float ts = timesteps[(size_t)b * LL + l];

    float dj[64];
    #pragma unroll
    for (int j = 0; j < 64; ++j) {
        float kj = fmaf(ts, w8_s[j], b8_s[j]);
        dj[j] = __sinf(kj) - kj;
    }

    int wid = tid >> 6, lane = tid & 63;
    for (int hp = 0; hp < HP; ++hp) {
        float acc = fmaf(ts, wA_s[hp], wB_s[hp]) + sb_s[hp];
        #pragma unroll
        for (int j0 = 0; j0 < 64; j0 += 4) {
            float4 v4 = *(const float4*)&vs_s[hp * 64 + j0];
            acc += dj[j0] * v4.x + dj[j0 + 1] * v4.y + dj[j0 + 2] * v4.z + dj[j0 + 3] * v4.w;
        }
        scores[((size_t)b * HP + hp) * LL + l] = acc;
        float m = acc;
        #pragma unroll
        for (int off = 32; off > 0; off >>= 1) m = fmaxf(m, __shfl_xor(m, off));
        if (lane == 0) wmax_s[hp][wid] = m;
    }
    __syncthreads();
    if (tid < HP)
        pmax[((size_t)b * 8 + seg) * HP + tid] =
            fmaxf(fmaxf(wmax_s[tid][0], wmax_s[tid][1]), fmaxf(wmax_s[tid][2], wmax_s[tid][3]));
}

// K5: per-chunk partial weighted sums: part[b][ch][hp][0:128]=num, [128:256]=den
__global__ __launch_bounds__(256) void k_wsum(const float* __restrict__ scores,
                                              const float* __restrict__ pmax,
                                              const float* __restrict__ X,
                                              const float* __restrict__ M,
                                              float* __restrict__ part) {
    int b = blockIdx.x / CH, ch = blockIdx.x % CH;
    int l0 = ch * CL, tid = threadIdx.x;
    __shared__ float m_s[HP];
    __shared__ float w_s[HP][CL];   // 24 KB
    if (tid < HP) {
        float m = -INFINITY;
        for (int s = 0; s < 8; ++s) m = fmaxf(m, pmax[((size_t)b * 8 + s) * HP + tid]);
        m_s[tid] = m;
    }
    __syncthreads();
    for (int i = tid; i < HP * CL; i += 256) {
        int hp = i / CL, lc = i % CL;
        w_s[hp][lc] = __expf(scores[((size_t)b * HP + hp) * LL + l0 + lc] - m_s[hp]);
    }
    __syncthreads();

    int c = tid & 127;
    int hh = tid >> 7;   // hp half: 12*hh .. 12*hh+11
    float accn[12], accd[12];
    #pragma unroll
    for (int i = 0; i < 12; ++i) { accn[i] = 0.f; accd[i] = 0.f; }

    for (int lc = 0; lc < CL; lc += 4) {
        float mv[4], xv[4];
        #pragma unroll
        for (int j = 0; j < 4; ++j) {
            size_t l = (size_t)b * LL + l0 + lc + j;
            mv[j] = M[l * D + c];
            xv[j] = X[l * D + c] * mv[j];
        }
        #pragma unroll
        for (int i = 0; i < 12; ++i) {
            const float4 w4 = *(const float4*)&w_s[12 * hh + i][lc];
            accn[i] += w4.x * xv[0] + w4.y * xv[1] + w4.z * xv[2] + w4.w * xv[3];
            accd[i] += w4.x * mv[0] + w4.y * mv[1] + w4.z * mv[2] + w4.w * mv[3];
        }
    }
    #pragma unroll
    for (int i = 0; i < 12; ++i) {
        int hp = 12 * hh + i;
        size_t base = ((size_t)(b * CH + ch) * HP + hp) * 256;
        part[base + c]       = accn[i];
        part[base + 128 + c] = accd[i];
    }
}

// K6a: per (b,h): ratio = num/den (with inline chunk reduce), partial W_o matmul
__global__ __launch_bounds__(256) void k_coefp(const float* __restrict__ part,
                                               const float* __restrict__ W_o,
                                               float* __restrict__ part2) {
    int b = blockIdx.x, h = blockIdx.y;
    int tid = threadIdx.x;
    __shared__ float ratio[PP][D];   // 1.5 KB
    for (int ii = tid; ii < PP * D; ii += 256) {
        int p = ii >> 7, c = ii & 127;
        int hp = h * PP + p;
        float n = 0.f, d = 0.f;
        for (int ch = 0; ch < CH; ++ch) {
            size_t base = ((size_t)(b * CH + ch) * HP + hp) * 256;
            n += part[base + c];
            d += part[base + 128 + c];
        }
        ratio[p][c] = n / d;
    }
    __syncthreads();
    int o = tid;
    float a0 = 0.f, a1 = 0.f, a2 = 0.f;
    #pragma unroll 4
    for (int c = 0; c < D; ++c) {
        float w = W_o[(size_t)(h * 256 + c) * LAT + o];
        a0 = fmaf(ratio[0][c], w, a0);
        a1 = fmaf(ratio[1][c], w, a1);
        a2 = fmaf(ratio[2][c], w, a2);
    }
    size_t base = (((size_t)b * NH + h) * PP) * LAT + o;
    part2[base]           = a0;
    part2[base + LAT]     = a1;
    part2[base + 2 * LAT] = a2;
}

// K6b: coeffs[b][p][o] = Cvec[o] + sum_h part2[b][h][p][o]
__global__ __launch_bounds__(256) void k_cred(const float* __restrict__ part2,
                                              const float* __restrict__ Cvec,
                                              float* __restrict__ coeffs) {
    int b = blockIdx.x, o = threadIdx.x;
    float cv = Cvec[o];
    for (int p = 0; p < PP; ++p) {
        float s = cv;
        for (int h = 0; h < NH; ++h)
            s += part2[(((size_t)b * NH + h) * PP + p) * LAT + o];
        coeffs[((size_t)b * PP + p) * LAT + o] = s;
    }
}

// K5c: convert W2 -> W2T bf16 [n][k], W3 -> W3T bf16 [n][k]  (overlay on part)
__global__ __launch_bounds__(256) void k_cvt(const float* __restrict__ W2,
                                             const float* __restrict__ W3,
                                             ushort* __restrict__ W2T,
                                             ushort* __restrict__ W3T) {
    int idx = blockIdx.x * 256 + threadIdx.x;
    if (idx < HID * HID) {
        int k = idx >> 9, n = idx & 511;          // coalesced read of W2[k][n]
        W2T[(size_t)n * HID + k] = f2bf(W2[idx]);
    } else {
        int j = idx - HID * HID;                  // j < 512*128
        int k = j >> 7, n = j & 127;              // coalesced read of W3[k][n]
        W3T[(size_t)n * HID + k] = f2bf(W3[j]);
    }
}

// K7: a[b][i][j] = coeffs[b][i]@W1[:,j] (+ b1 for i==0)
__global__ __launch_bounds__(512) void k_avec(const float* __restrict__ coeffs,
                                              const float* __restrict__ W1,
                                              const float* __restrict__ b1,
                                              float* __restrict__ abuf) {
    int b = blockIdx.x / 3, i = blockIdx.x % 3;
    int j = threadIdx.x;
    float acc = (i == 0) ? b1[j] : 0.f;
    for (int k = 0; k < LAT; ++k)
        acc += coeffs[((size_t)b * PP + i) * LAT + k] * W1[(size_t)k * HID + j];
    abuf[((size_t)b * 3 + i) * HID + j] = acc;
}

// K8: fused MFMA MLP. 64-row tile, 256 thr, 64 KiB LDS (h1 then h2), 2 blocks/CU.
// GEMM1 operand-swapped: D[j][r] = sum_k W2T[j][k]*h1[r][k]  -> b64 LDS stores of h2.
__global__ __launch_bounds__(256, 2) void k_mlp3(const float* __restrict__ abuf,
                                                 const float* __restrict__ yts,
                                                 const ushort* __restrict__ W2T,
                                                 const float* __restrict__ b2,
                                                 const ushort* __restrict__ W3T,
                                                 const float* __restrict__ b3,
                                                 float* __restrict__ out) {
    __shared__ ushort hbuf[64 * HID];   // 64 KiB, XOR-swizzled (byte ^= (r&7)<<4)
    int b = blockIdx.x;
    int t0 = blockIdx.y * 64;
    int tid = threadIdx.x;
    const float* a0p = abuf + (size_t)b * 3 * HID;
    const float* a1p = a0p + HID;
    const float* a2p = a1p + HID;

    // phase A: h1 = relu(a0 + t*a1 + t^2*a2) -> bf16 LDS row-major [r][k]
    {
        int r = tid >> 2, cg = tid & 3;
        float t = yts[(size_t)b * TT + t0 + r];
        int c0 = cg * 128;
        #pragma unroll
        for (int i = 0; i < 32; ++i) {
            int c = c0 + i * 4;
            float4 x0 = *(const float4*)&a0p[c];
            float4 x1 = *(const float4*)&a1p[c];
            float4 x2 = *(const float4*)&a2p[c];
            float z0 = fmaxf(x0.x + t * (x1.x + t * x2.x), 0.f);
            float z1 = fmaxf(x0.y + t * (x1.y + t * x2.y), 0.f);
            float z2 = fmaxf(x0.z + t * (x1.z + t * x2.z), 0.f);
            float z3 = fmaxf(x0.w + t * (x1.w + t * x2.w), 0.f);
            uint lo = (uint)f2bf(z0) | ((uint)f2bf(z1) << 16);
            uint hi2 = (uint)f2bf(z2) | ((uint)f2bf(z3) << 16);
            uint byte = ((uint)(r * 1024 + c * 2)) ^ ((uint)(r & 7) << 4);
            *(uint2*)((char*)hbuf + byte) = make_uint2(lo, hi2);
        }
    }
    __syncthreads();

    int wid = tid >> 6, lane = tid & 63;
    int ln = lane & 15, hi = lane >> 4;

    // ---- GEMM1: wave wid covers j in [wid*128, +128), r all 64 ----
    f32x4 acc[8][4];
    #pragma unroll
    for (int jf = 0; jf < 8; ++jf) {
        float4 bv = *(const float4*)&b2[wid * 128 + jf * 16 + 4 * hi];
        #pragma unroll
        for (int rf = 0; rf < 4; ++rf) acc[jf][rf] = (f32x4){bv.x, bv.y, bv.z, bv.w};
    }
    for (int k0 = 0; k0 < HID; k0 += 32) {
        bf16x8 af[8], bh[4];
        #pragma unroll
        for (int jf = 0; jf < 8; ++jf) {
            int j = wid * 128 + jf * 16 + ln;
            af[jf] = *(const bf16x8*)(W2T + (size_t)j * HID + k0 + 8 * hi);
        }
        #pragma unroll
        for (int rf = 0; rf < 4; ++rf) {
            int r = rf * 16 + ln;
            uint byte = ((uint)(r * 1024 + (k0 + 8 * hi) * 2)) ^ ((uint)(r & 7) << 4);
            bh[rf] = *(const bf16x8*)((const char*)hbuf + byte);
        }
        #pragma unroll
        for (int jf = 0; jf < 8; ++jf)
            #pragma unroll
            for (int rf = 0; rf < 4; ++rf)
                acc[jf][rf] = __builtin_amdgcn_mfma_f32_16x16x32_bf16(af[jf], bh[rf], acc[jf][rf], 0, 0, 0);
    }
    __syncthreads();   // all h1 reads done

    // phase C: h2 = relu(acc) -> bf16 LDS row-major [r][j] via b64 stores
    #pragma unroll
    for (int jf = 0; jf < 8; ++jf)
        #pragma unroll
        for (int rf = 0; rf < 4; ++rf) {
            int r = rf * 16 + ln;
            int jcol = wid * 128 + jf * 16 + 4 * hi;
            uint pk0 = (uint)f2bf(fmaxf(acc[jf][rf][0], 0.f)) | ((uint)f2bf(fmaxf(acc[jf][rf][1], 0.f)) << 16);
            uint pk1 = (uint)f2bf(fmaxf(acc[jf][rf][2], 0.f)) | ((uint)f2bf(fmaxf(acc[jf][rf][3], 0.f)) << 16);
            uint byte = ((uint)(r * 1024 + jcol * 2)) ^ ((uint)(r & 7) << 4);
            *(uint2*)((char*)hbuf + byte) = make_uint2(pk0, pk1);
        }
    __syncthreads();

    // ---- GEMM2: wave wid covers rows [wid*16, +16), cols 128 ----
    f32x4 acc2[8];
    #pragma unroll
    for (int n = 0; n < 8; ++n) {
        float bv = b3[n * 16 + ln];
        acc2[n] = (f32x4){bv, bv, bv, bv};
    }
    for (int k0 = 0; k0 < HID; k0 += 32) {
        int r = wid * 16 + ln;
        uint byte = ((uint)(r * 1024 + (k0 + 8 * hi) * 2)) ^ ((uint)(r & 7) << 4);
        bf16x8 ah = *(const bf16x8*)((const char*)hbuf + byte);
        #pragma unroll
        for (int n = 0; n < 8; ++n) {
            bf16x8 bw = *(const bf16x8*)(W3T + (size_t)(n * 16 + ln) * HID + k0 + 8 * hi);
            acc2[n] = __builtin_amdgcn_mfma_f32_16x16x32_bf16(ah, bw, acc2[n], 0, 0, 0);
        }
    }
    #pragma unroll
    for (int n = 0; n < 8; ++n)
        #pragma unroll
        for (int reg = 0; reg < 4; ++reg) {
            int r = wid * 16 + 4 * hi + reg;
            int c = n * 16 + ln;
            out[((size_t)(b * TT + t0 + r)) * D + c] = acc2[n][reg];
        }
}

extern "C" void kernel_launch(void* const* d_in, const int* in_sizes, int n_in,
                              void* d_out, int out_size, void* d_ws, size_t ws_size,
                              hipStream_t stream) {
    const float* timesteps = (const float*)d_in[0];
    const float* X        = (const float*)d_in[1];
    const float* M        = (const float*)d_in[2];
    const float* yts      = (const float*)d_in[3];
    const float* w_te     = (const float*)d_in[4];
    const float* b_te     = (const float*)d_in[5];
    const float* query    = (const float*)d_in[6];
    const float* W_q      = (const float*)d_in[7];
    const float* b_q      = (const float*)d_in[8];
    const float* W_k      = (const float*)d_in[9];
    const float* b_k      = (const float*)d_in[10];
    const float* W_o      = (const float*)d_in[11];
    const float* b_o      = (const float*)d_in[12];
    const float* W1       = (const float*)d_in[13];
    const float* b1       = (const float*)d_in[14];
    const float* W2       = (const float*)d_in[15];
    const float* b2       = (const float*)d_in[16];
    const float* W3       = (const float*)d_in[17];
    const float* b3       = (const float*)d_in[18];
    float* out = (float*)d_out;
    float* ws  = (float*)d_ws;

    float* qbuf   = ws + OFF_Q;
    float* vsin   = ws + OFF_VS;
    float* wA     = ws + OFF_WA;
    float* wB     = ws + OFF_WB;
    float* sbias  = ws + OFF_SB;
    float* Cvec   = ws + OFF_CV;
    float* pmax   = ws + OFF_PMAX;
    float* coeffs = ws + OFF_COEF;
    float* part2  = ws + OFF_P2;
    float* abuf   = ws + OFF_A;        // overlays part2 (dead after k_cred)
    float* part   = ws + OFF_PART;
    float* scores = ws + OFF_SC;
    ushort* W2T   = (ushort*)(ws + OFF_PART);   // overlays part (dead after k_coefp)
    ushort* W3T   = W2T + (size_t)HID * HID;

    hipLaunchKernelGGL(k_q,      dim3(PP),          dim3(512), 0, stream, query, W_q, b_q, qbuf);
    hipLaunchKernelGGL(k_v,      dim3(HP),          dim3(512), 0, stream, W_k, b_k, qbuf, w_te, b_te, vsin, wA, wB, sbias);
    hipLaunchKernelGGL(k_cvec,   dim3(1),           dim3(256), 0, stream, W_o, b_o, Cvec);
    hipLaunchKernelGGL(k_scores, dim3(BB * 8),      dim3(256), 0, stream, timesteps, w_te, b_te, vsin, wA, wB, sbias, scores, pmax);
    hipLaunchKernelGGL(k_wsum,   dim3(BB * CH),     dim3(256), 0, stream, scores, pmax, X, M, part);
    hipLaunchKernelGGL(k_coefp,  dim3(BB, NH),      dim3(256), 0, stream, part, W_o, part2);
    hipLaunchKernelGGL(k_cred,   dim3(BB),          dim3(256), 0, stream, part2, Cvec, coeffs);
    hipLaunchKernelGGL(k_cvt,    dim3((HID * HID + HID * D) / 256), dim3(256), 0, stream, W2, W3, W2T, W3T);
    hipLaunchKernelGGL(k_avec,   dim3(BB * 3),      dim3(512), 0, stream, coeffs, W1, b1, abuf);
    hipLaunchKernelGGL(k_mlp3,   dim3(BB, TT / 64), dim3(256), 0, stream, abuf, yts, W2T, b2, W3T, b3, out);
}

// Round 4
// 223.512 us; speedup vs baseline: 4.1556x; 1.4939x over previous
//
#include <hip/hip_runtime.h>
#include <math.h>

#define NH   8
#define PP   3
#define HP   24      // NH*PP
#define E    512
#define EK   64
#define D    128
#define LL   2048
#define BB   64
#define TT   1024
#define LAT  256
#define HID  512
#define CH   8       // l-chunks in weighted-sum pass
#define CL   256     // chunk length

typedef __attribute__((ext_vector_type(8))) short bf16x8;
typedef __attribute__((ext_vector_type(4))) float f32x4;

// ---- workspace offsets (in floats) ----
#define OFF_Q      ((size_t)0)            // 1536
#define OFF_VS     ((size_t)2048)         // 1536 (vsin 24x64)
#define OFF_WA     ((size_t)4096)         // 24
#define OFF_WB     ((size_t)4128)         // 24
#define OFF_SB     ((size_t)4160)         // 24
#define OFF_CV     ((size_t)4224)         // 256
#define OFF_PMAX   ((size_t)4608)         // 12288 (64 x 8 x 24)
#define OFF_COEF   ((size_t)24576)        // 49152
#define OFF_CVP    ((size_t)73728)        // 8192 (cvec partials)
#define OFF_P2     ((size_t)81920)        // 393216 (part2; abuf overlays after k_cred)
#define OFF_A      ((size_t)81920)        // 98304  (abuf, overlays part2)
#define OFF_PART   ((size_t)475136)       // 3145728 (part)
#define OFF_SC     ((size_t)3620864)      // 3145728 (scores; W2F/W3F overlay after k_wsum)

__device__ inline ushort f2bf(float x) {
    union { float f; uint u; } v; v.f = x;
    uint r = v.u + 0x7fffu + ((v.u >> 16) & 1u);
    return (ushort)(r >> 16);
}
__device__ inline uint swz(uint a) { return a ^ (((a >> 9) & 7u) << 4); }
__device__ inline uint pk2(float lo, float hi) {
    return (uint)f2bf(lo) | ((uint)f2bf(hi) << 16);
}
__device__ inline float h1f(float a0, float a1, float a2, float t) {
    return fmaxf(fmaf(t, fmaf(t, a2, a1), a0), 0.f);
}

// K1: q[p][e] = query[p]@W_q + b_q   (batch-independent)
__global__ __launch_bounds__(512) void k_q(const float* __restrict__ query,
                                           const float* __restrict__ W_q,
                                           const float* __restrict__ b_q,
                                           float* __restrict__ qbuf) {
    int p = blockIdx.x, e = threadIdx.x;
    float acc = b_q[e];
    for (int i = 0; i < E; ++i) acc += query[p * E + i] * W_q[(size_t)i * E + e];
    qbuf[p * E + e] = acc;
}

// K2: per (hp): v[e] = (1/8)*sum_j W_k[e][h*64+j] q[p][..]; emit vsin (e%8==0 cols),
//     wA = sum v*w_te, wB = sum v*b_te, sbias.
__global__ __launch_bounds__(512) void k_v(const float* __restrict__ W_k,
                                           const float* __restrict__ b_k,
                                           const float* __restrict__ qbuf,
                                           const float* __restrict__ w_te,
                                           const float* __restrict__ b_te,
                                           float* __restrict__ vsin,
                                           float* __restrict__ wA,
                                           float* __restrict__ wB,
                                           float* __restrict__ sbias) {
    int hp = blockIdx.x;
    int h = hp / PP, p = hp % PP;
    int e = threadIdx.x;
    const float scale = 0.125f;  // 1/sqrt(64)
    float acc = 0.f;
    for (int j = 0; j < EK; ++j)
        acc += W_k[(size_t)e * E + h * EK + j] * qbuf[p * E + h * EK + j];
    float v = acc * scale;
    if ((e & 7) == 0) vsin[hp * 64 + (e >> 3)] = v;
    __shared__ float r1[512], r2[512];
    r1[e] = v * w_te[e];
    r2[e] = v * b_te[e];
    __syncthreads();
    for (int s = 256; s > 0; s >>= 1) {
        if (e < s) { r1[e] += r1[e + s]; r2[e] += r2[e + s]; }
        __syncthreads();
    }
    if (e == 0) {
        wA[hp] = r1[0];
        wB[hp] = r2[0];
        float sb = 0.f;
        for (int j = 0; j < EK; ++j) sb += b_k[h * EK + j] * qbuf[p * E + h * EK + j];
        sbias[hp] = sb * scale;
    }
}

// K2b: parallel Cvec partials: cvp[h*4+cc][o] = sum_{c in chunk} W_o[h*256+128+c][o]
__global__ __launch_bounds__(256) void k_cvp(const float* __restrict__ W_o,
                                             float* __restrict__ cvp) {
    int h = blockIdx.x, cc = blockIdx.y, o = threadIdx.x;
    float acc = 0.f;
    #pragma unroll 8
    for (int c = cc * 32; c < cc * 32 + 32; ++c)
        acc += W_o[(size_t)(h * 256 + 128 + c) * LAT + o];
    cvp[(h * 4 + cc) * LAT + o] = acc;
}

// K2c: Cvec[o] = b_o[o] + sum_32 cvp
__global__ __launch_bounds__(256) void k_cvr(const float* __restrict__ cvp,
                                             const float* __restrict__ b_o,
                                             float* __restrict__ Cvec) {
    int o = threadIdx.x;
    float acc = b_o[o];
    #pragma unroll
    for (int i = 0; i < 32; ++i) acc += cvp[i * LAT + o];
    Cvec[o] = acc;
}

// K3: scores[b][hp][l] = ts*wA[hp] + wB[hp] + sb[hp] + sum_j (sin(kj)-kj)*vsin[hp][j]
//     + per-(b,seg) partial max -> pmax
__global__ __launch_bounds__(256) void k_scores(const float* __restrict__ timesteps,
                                                const float* __restrict__ w_te,
                                                const float* __restrict__ b_te,
                                                const float* __restrict__ vsin,
                                                const float* __restrict__ wA,
                                                const float* __restrict__ wB,
                                                const float* __restrict__ sb,
                                                float* __restrict__ scores,
                                                float* __restrict__ pmax) {
    __shared__ float vs_s[HP * 64];   // 6 KB
    __shared__ float w8_s[64], b8_s[64];
    __shared__ float wA_s[HP], wB_s[HP], sb_s[HP];
    __shared__ float wmax_s[HP][4];
    int tid = threadIdx.x;
    for (int i = tid; i < HP * 64; i += 256) vs_s[i] = vsin[i];
    if (tid < 64) { w8_s[tid] = w_te[tid * 8]; b8_s[tid] = b_te[tid * 8]; }
    if (tid < HP) { wA_s[tid] = wA[tid]; wB_s[tid] = wB[tid]; sb_s[tid] = sb[tid]; }
    __syncthreads();

    int b = blockIdx.x >> 3, seg = blockIdx.x & 7;
    int l = seg * 256 + tid;
    float ts = timesteps[(size_t)b * LL + l];

    float dj[64];
    #pragma unroll
    for (int j = 0; j < 64; ++j) {
        float kj = fmaf(ts, w8_s[j], b8_s[j]);
        dj[j] = __sinf(kj) - kj;
    }

    int wid = tid >> 6, lane = tid & 63;
    for (int hp = 0; hp < HP; ++hp) {
        float acc = fmaf(ts, wA_s[hp], wB_s[hp]) + sb_s[hp];
        #pragma unroll
        for (int j0 = 0; j0 < 64; j0 += 4) {
            float4 v4 = *(const float4*)&vs_s[hp * 64 + j0];
            acc += dj[j0] * v4.x + dj[j0 + 1] * v4.y + dj[j0 + 2] * v4.z + dj[j0 + 3] * v4.w;
        }
        scores[((size_t)b * HP + hp) * LL + l] = acc;
        float m = acc;
        #pragma unroll
        for (int off = 32; off > 0; off >>= 1) m = fmaxf(m, __shfl_xor(m, off));
        if (lane == 0) wmax_s[hp][wid] = m;
    }
    __syncthreads();
    if (tid < HP)
        pmax[((size_t)b * 8 + seg) * HP + tid] =
            fmaxf(fmaxf(wmax_s[tid][0], wmax_s[tid][1]), fmaxf(wmax_s[tid][2], wmax_s[tid][3]));
}

// K5: per-chunk partial weighted sums: part[b][ch][hp][0:128]=num, [128:256]=den
__global__ __launch_bounds__(256) void k_wsum(const float* __restrict__ scores,
                                              const float* __restrict__ pmax,
                                              const float* __restrict__ X,
                                              const float* __restrict__ M,
                                              float* __restrict__ part) {
    int b = blockIdx.x / CH, ch = blockIdx.x % CH;
    int l0 = ch * CL, tid = threadIdx.x;
    __shared__ float m_s[HP];
    __shared__ float w_s[HP][CL];   // 24 KB
    if (tid < HP) {
        float m = -INFINITY;
        for (int s = 0; s < 8; ++s) m = fmaxf(m, pmax[((size_t)b * 8 + s) * HP + tid]);
        m_s[tid] = m;
    }
    __syncthreads();
    for (int i = tid; i < HP * CL; i += 256) {
        int hp = i / CL, lc = i % CL;
        w_s[hp][lc] = __expf(scores[((size_t)b * HP + hp) * LL + l0 + lc] - m_s[hp]);
    }
    __syncthreads();

    int c = tid & 127;
    int hh = tid >> 7;   // hp half: 12*hh .. 12*hh+11
    float accn[12], accd[12];
    #pragma unroll
    for (int i = 0; i < 12; ++i) { accn[i] = 0.f; accd[i] = 0.f; }

    for (int lc = 0; lc < CL; lc += 4) {
        float mv[4], xv[4];
        #pragma unroll
        for (int j = 0; j < 4; ++j) {
            size_t l = (size_t)b * LL + l0 + lc + j;
            mv[j] = M[l * D + c];
            xv[j] = X[l * D + c] * mv[j];
        }
        #pragma unroll
        for (int i = 0; i < 12; ++i) {
            const float4 w4 = *(const float4*)&w_s[12 * hh + i][lc];
            accn[i] += w4.x * xv[0] + w4.y * xv[1] + w4.z * xv[2] + w4.w * xv[3];
            accd[i] += w4.x * mv[0] + w4.y * mv[1] + w4.z * mv[2] + w4.w * mv[3];
        }
    }
    #pragma unroll
    for (int i = 0; i < 12; ++i) {
        int hp = 12 * hh + i;
        size_t base = ((size_t)(b * CH + ch) * HP + hp) * 256;
        part[base + c]       = accn[i];
        part[base + 128 + c] = accd[i];
    }
}

// K6a: per (b,h): ratio = num/den (with inline chunk reduce), partial W_o matmul
__global__ __launch_bounds__(256) void k_coefp(const float* __restrict__ part,
                                               const float* __restrict__ W_o,
                                               float* __restrict__ part2) {
    int b = blockIdx.x, h = blockIdx.y;
    int tid = threadIdx.x;
    __shared__ float ratio[PP][D];   // 1.5 KB
    for (int ii = tid; ii < PP * D; ii += 256) {
        int p = ii >> 7, c = ii & 127;
        int hp = h * PP + p;
        float n = 0.f, d = 0.f;
        for (int ch = 0; ch < CH; ++ch) {
            size_t base = ((size_t)(b * CH + ch) * HP + hp) * 256;
            n += part[base + c];
            d += part[base + 128 + c];
        }
        ratio[p][c] = n / d;
    }
    __syncthreads();
    int o = tid;
    float a0 = 0.f, a1 = 0.f, a2 = 0.f;
    #pragma unroll 4
    for (int c = 0; c < D; ++c) {
        float w = W_o[(size_t)(h * 256 + c) * LAT + o];
        a0 = fmaf(ratio[0][c], w, a0);
        a1 = fmaf(ratio[1][c], w, a1);
        a2 = fmaf(ratio[2][c], w, a2);
    }
    size_t base = (((size_t)b * NH + h) * PP) * LAT + o;
    part2[base]           = a0;
    part2[base + LAT]     = a1;
    part2[base + 2 * LAT] = a2;
}

// K6b: coeffs[b][p][o] = Cvec[o] + sum_h part2[b][h][p][o]
__global__ __launch_bounds__(256) void k_cred(const float* __restrict__ part2,
                                              const float* __restrict__ Cvec,
                                              float* __restrict__ coeffs) {
    int b = blockIdx.x, o = threadIdx.x;
    float cv = Cvec[o];
    for (int p = 0; p < PP; ++p) {
        float s = cv;
        for (int h = 0; h < NH; ++h)
            s += part2[(((size_t)b * NH + h) * PP + p) * LAT + o];
        coeffs[((size_t)b * PP + p) * LAT + o] = s;
    }
}

// K5c: build fragment-major bf16 weights.
// W2F frag (S,JT): lane l elem e = W2[S*32 + 8*(l>>4)+e][JT*16 + (l&15)]
// W3F frag (S2,NT): lane l elem e = W3[S2*32 + 8*(l>>4)+e][NT*16 + (l&15)]
__global__ __launch_bounds__(256) void k_cvt(const float* __restrict__ W2,
                                             const float* __restrict__ W3,
                                             ushort* __restrict__ W2F,
                                             ushort* __restrict__ W3F) {
    int gid = blockIdx.x * 256 + threadIdx.x;
    int l = gid & 63;
    int kbase = 8 * (l >> 4);
    int cbase = l & 15;
    if (gid < 32768) {
        int t = gid >> 6;        // 0..511
        int JT = t & 31, S = t >> 5;
        #pragma unroll
        for (int e = 0; e < 8; ++e)
            W2F[(size_t)gid * 8 + e] = f2bf(W2[(size_t)(S * 32 + kbase + e) * HID + JT * 16 + cbase]);
    } else {
        int g2 = gid - 32768;    // 0..8191
        int t = g2 >> 6;         // 0..127
        int NT = t & 7, S2 = t >> 3;
        #pragma unroll
        for (int e = 0; e < 8; ++e)
            W3F[(size_t)g2 * 8 + e] = f2bf(W3[(size_t)(S2 * 32 + kbase + e) * D + NT * 16 + cbase]);
    }
}

// K7: a[b][i][j] = coeffs[b][i]@W1[:,j] (+ b1 for i==0); one block per b reads W1 once
__global__ __launch_bounds__(512) void k_avec3(const float* __restrict__ coeffs,
                                               const float* __restrict__ W1,
                                               const float* __restrict__ b1,
                                               float* __restrict__ abuf) {
    int b = blockIdx.x, j = threadIdx.x;
    const float* cf = coeffs + (size_t)b * PP * LAT;
    float a0 = b1[j], a1 = 0.f, a2 = 0.f;
    #pragma unroll 4
    for (int k = 0; k < LAT; ++k) {
        float w = W1[(size_t)k * HID + j];
        a0 = fmaf(cf[k], w, a0);
        a1 = fmaf(cf[LAT + k], w, a1);
        a2 = fmaf(cf[2 * LAT + k], w, a2);
    }
    abuf[(size_t)b * 3 * HID + j] = a0;
    abuf[(size_t)b * 3 * HID + HID + j] = a1;
    abuf[(size_t)b * 3 * HID + 2 * HID + j] = a2;
}

// K8: fused MFMA MLP. 64 rows/block, 256 thr, 32 KiB LDS (h1 <-> h2 reuse), swizzled.
// GEMM1 operand-swapped (m=j, n=row): acc[jt][rf]; j-split (jh) and k-split (kh) loops.
__global__ __launch_bounds__(256, 2) void k_mlp4(const float* __restrict__ abuf,
                                                 const float* __restrict__ yts,
                                                 const ushort* __restrict__ W2F,
                                                 const float* __restrict__ b2,
                                                 const ushort* __restrict__ W3F,
                                                 const float* __restrict__ b3,
                                                 float* __restrict__ out) {
    __shared__ char lds[32768];
    int b = blockIdx.x, t0 = blockIdx.y * 64, tid = threadIdx.x;
    const float* a0p = abuf + (size_t)b * 3 * HID;
    const float* a1p = a0p + HID;
    const float* a2p = a1p + HID;
    int lane = tid & 63, wj = tid >> 6;
    int ln = lane & 15, hi = lane >> 4;
    int r_pa = tid >> 2, q_pa = tid & 3;
    float t_pa = yts[(size_t)b * TT + t0 + r_pa];

    f32x4 acc2[8];
    #pragma unroll
    for (int nt = 0; nt < 8; ++nt) {
        float bv = b3[nt * 16 + ln];
        acc2[nt] = (f32x4){bv, bv, bv, bv};
    }

    for (int jh = 0; jh < 2; ++jh) {
        f32x4 acc[4][4];
        #pragma unroll
        for (int jt = 0; jt < 4; ++jt) {
            float4 bv = *(const float4*)&b2[jh * 256 + wj * 64 + jt * 16 + 4 * hi];
            #pragma unroll
            for (int rf = 0; rf < 4; ++rf) acc[jt][rf] = (f32x4){bv.x, bv.y, bv.z, bv.w};
        }
        for (int kh = 0; kh < 2; ++kh) {
            // phase A: h1[64 rows][k-half 256] -> LDS (conflict-free interleave)
            #pragma unroll
            for (int i = 0; i < 8; ++i) {
                int ko = (i * 4 + q_pa) * 8;   // 0..255, 16B-granular interleave
                int k = kh * 256 + ko;
                float4 x0a = *(const float4*)&a0p[k], x0b = *(const float4*)&a0p[k + 4];
                float4 x1a = *(const float4*)&a1p[k], x1b = *(const float4*)&a1p[k + 4];
                float4 x2a = *(const float4*)&a2p[k], x2b = *(const float4*)&a2p[k + 4];
                uint4 pk;
                pk.x = pk2(h1f(x0a.x, x1a.x, x2a.x, t_pa), h1f(x0a.y, x1a.y, x2a.y, t_pa));
                pk.y = pk2(h1f(x0a.z, x1a.z, x2a.z, t_pa), h1f(x0a.w, x1a.w, x2a.w, t_pa));
                pk.z = pk2(h1f(x0b.x, x1b.x, x2b.x, t_pa), h1f(x0b.y, x1b.y, x2b.y, t_pa));
                pk.w = pk2(h1f(x0b.z, x1b.z, x2b.z, t_pa), h1f(x0b.w, x1b.w, x2b.w, t_pa));
                *(uint4*)(lds + swz((uint)(r_pa * 512 + ko * 2))) = pk;
            }
            __syncthreads();
            #pragma unroll
            for (int s = 0; s < 8; ++s) {
                bf16x8 af[4], bh[4];
                #pragma unroll
                for (int jt = 0; jt < 4; ++jt)
                    af[jt] = *(const bf16x8*)(W2F + ((size_t)((kh * 8 + s) * 32 + jh * 16 + wj * 4 + jt) * 64 + lane) * 8);
                #pragma unroll
                for (int rf = 0; rf < 4; ++rf)
                    bh[rf] = *(const bf16x8*)(lds + swz((uint)((rf * 16 + ln) * 512 + s * 64 + hi * 16)));
                #pragma unroll
                for (int jt = 0; jt < 4; ++jt)
                    #pragma unroll
                    for (int rf = 0; rf < 4; ++rf)
                        acc[jt][rf] = __builtin_amdgcn_mfma_f32_16x16x32_bf16(af[jt], bh[rf], acc[jt][rf], 0, 0, 0);
            }
            __syncthreads();
        }
        // phase C: h2 = relu(acc) -> LDS [64 r][256 j-half] bf16, packed b64 along j
        #pragma unroll
        for (int jt = 0; jt < 4; ++jt)
            #pragma unroll
            for (int rf = 0; rf < 4; ++rf) {
                int r = rf * 16 + ln;
                int bo = (wj * 64 + jt * 16 + 4 * hi) * 2;
                uint p0 = pk2(fmaxf(acc[jt][rf][0], 0.f), fmaxf(acc[jt][rf][1], 0.f));
                uint p1 = pk2(fmaxf(acc[jt][rf][2], 0.f), fmaxf(acc[jt][rf][3], 0.f));
                *(uint2*)(lds + swz((uint)(r * 512 + bo))) = make_uint2(p0, p1);
            }
        __syncthreads();
        // GEMM2 partial: acc2 += h2[:, jh-half] @ W3[jh-half, :]
        #pragma unroll
        for (int s2 = 0; s2 < 8; ++s2) {
            bf16x8 ah = *(const bf16x8*)(lds + swz((uint)((wj * 16 + ln) * 512 + s2 * 64 + hi * 16)));
            #pragma unroll
            for (int nt = 0; nt < 8; ++nt) {
                bf16x8 bw = *(const bf16x8*)(W3F + ((size_t)((jh * 8 + s2) * 8 + nt) * 64 + lane) * 8);
                acc2[nt] = __builtin_amdgcn_mfma_f32_16x16x32_bf16(ah, bw, acc2[nt], 0, 0, 0);
            }
        }
        __syncthreads();
    }
    #pragma unroll
    for (int nt = 0; nt < 8; ++nt)
        #pragma unroll
        for (int reg = 0; reg < 4; ++reg)
            out[((size_t)b * TT + t0 + wj * 16 + 4 * hi + reg) * D + nt * 16 + ln] = acc2[nt][reg];
}

extern "C" void kernel_launch(void* const* d_in, const int* in_sizes, int n_in,
                              void* d_out, int out_size, void* d_ws, size_t ws_size,
                              hipStream_t stream) {
    const float* timesteps = (const float*)d_in[0];
    const float* X        = (const float*)d_in[1];
    const float* M        = (const float*)d_in[2];
    const float* yts      = (const float*)d_in[3];
    const float* w_te     = (const float*)d_in[4];
    const float* b_te     = (const float*)d_in[5];
    const float* query    = (const float*)d_in[6];
    const float* W_q      = (const float*)d_in[7];
    const float* b_q      = (const float*)d_in[8];
    const float* W_k      = (const float*)d_in[9];
    const float* b_k      = (const float*)d_in[10];
    const float* W_o      = (const float*)d_in[11];
    const float* b_o      = (const float*)d_in[12];
    const float* W1       = (const float*)d_in[13];
    const float* b1       = (const float*)d_in[14];
    const float* W2       = (const float*)d_in[15];
    const float* b2       = (const float*)d_in[16];
    const float* W3       = (const float*)d_in[17];
    const float* b3       = (const float*)d_in[18];
    float* out = (float*)d_out;
    float* ws  = (float*)d_ws;

    float* qbuf   = ws + OFF_Q;
    float* vsin   = ws + OFF_VS;
    float* wA     = ws + OFF_WA;
    float* wB     = ws + OFF_WB;
    float* sbias  = ws + OFF_SB;
    float* Cvec   = ws + OFF_CV;
    float* pmax   = ws + OFF_PMAX;
    float* coeffs = ws + OFF_COEF;
    float* cvp    = ws + OFF_CVP;
    float* part2  = ws + OFF_P2;
    float* abuf   = ws + OFF_A;        // overlays part2 (dead after k_cred)
    float* part   = ws + OFF_PART;
    float* scores = ws + OFF_SC;
    ushort* W2F   = (ushort*)(ws + OFF_SC);     // overlays scores (dead after k_wsum)
    ushort* W3F   = W2F + (size_t)HID * HID;

    hipLaunchKernelGGL(k_q,      dim3(PP),          dim3(512), 0, stream, query, W_q, b_q, qbuf);
    hipLaunchKernelGGL(k_v,      dim3(HP),          dim3(512), 0, stream, W_k, b_k, qbuf, w_te, b_te, vsin, wA, wB, sbias);
    hipLaunchKernelGGL(k_cvp,    dim3(NH, 4),       dim3(256), 0, stream, W_o, cvp);
    hipLaunchKernelGGL(k_cvr,    dim3(1),           dim3(256), 0, stream, cvp, b_o, Cvec);
    hipLaunchKernelGGL(k_scores, dim3(BB * 8),      dim3(256), 0, stream, timesteps, w_te, b_te, vsin, wA, wB, sbias, scores, pmax);
    hipLaunchKernelGGL(k_wsum,   dim3(BB * CH),     dim3(256), 0, stream, scores, pmax, X, M, part);
    hipLaunchKernelGGL(k_cvt,    dim3(160),         dim3(256), 0, stream, W2, W3, W2F, W3F);
    hipLaunchKernelGGL(k_coefp,  dim3(BB, NH),      dim3(256), 0, stream, part, W_o, part2);
    hipLaunchKernelGGL(k_cred,   dim3(BB),          dim3(256), 0, stream, part2, Cvec, coeffs);
    hipLaunchKernelGGL(k_avec3,  dim3(BB),          dim3(512), 0, stream, coeffs, W1, b1, abuf);
    hipLaunchKernelGGL(k_mlp4,   dim3(BB, TT / 64), dim3(256), 0, stream, abuf, yts, W2F, b2, W3F, b3, out);
}